// Round 13
// baseline (17.119 us; speedup 1.0000x reference)
//
#include <hip/hip_runtime.h>
#include <math.h>

// NN-MSE (one-directional Chamfer) via MFMA — SINGLE dispatch.
// k1 compute body identical to R8 (12.2us best, absmax 0). Tail replaced:
// per-block sum -> ONE relaxed fp32 atomicAdd to ws_sum (no release/acquire
// fences -> none of R4's L2-writeback cost), then ticket counter. Each block
// orders sum-add before counter-add with a lane-0 s_waitcnt vmcnt(0). The
// block drawing ticket == nblk-1 (mod nblk; poison-proof) re-reads the total
// via fetch_add(+0.0) — complete because every sum-add was acked before its
// counter-add, all of which precede the winner's ticket — writes out[0],
// and resets ws_sum=0 for the next graph replay (first call starts from
// poison 0xAA... = -3e-13f, negligible vs loss ~8).
//
// Math (verified R8): d2(n,m) = |s_n|^2 + (|t_m|^2 - 2 s_n.t_m); cross term
// by v_mfma_f32_32x32x16_f16:
//   A lanes<32: [shx,shy,shz,slx,sly,slz,1,1] (fp16 hi/lo split of src); >=32: 0
//   B col lane: [-2tx,-2ty,-2tz,-2tx,-2ty,-2tz,TNh,TNl] fp16, TN=|t|^2 hi/lo
//   C/D: col=lane&31, row=(reg&3)+8*(reg>>2)+4*(lane>>5)  [m74/m101]

#define THREADS 512
#define SRC_BLK 128
#define PART_STRIDE 18

typedef __attribute__((ext_vector_type(8))) _Float16 half8;
typedef __attribute__((ext_vector_type(16))) float f32x16;

__device__ __forceinline__ unsigned short f16b(float x) {
    _Float16 hv = (_Float16)x;
    return __builtin_bit_cast(unsigned short, hv);
}
__device__ __forceinline__ float f16tof(unsigned short u) {
    return (float)__builtin_bit_cast(_Float16, u);
}

__global__ __launch_bounds__(THREADS)
void nn_mfma_kernel(const float* __restrict__ coord,
                    const float* __restrict__ coord_t,
                    const float* __restrict__ Rm,
                    const float* __restrict__ tv,
                    float* __restrict__ sum_p,
                    unsigned int* __restrict__ cnt_p,
                    float* __restrict__ out,
                    int S, int NSC, int nblk, float scale) {
    __shared__ uint4 Bfrag[2048];                 // 32 KB: one 16B entry/target
    __shared__ float part[128 * PART_STRIDE];     // 9 KB, padded stride
    __shared__ float SN_lds[128];
    __shared__ float wsum[2];

    const int tid  = threadIdx.x;
    const int bid  = blockIdx.x;
    const int b    = bid / NSC;
    const int sc   = bid - b * NSC;
    const int w    = tid >> 6;
    const int lane = tid & 63;
    const int col  = lane & 31;
    const int kh   = lane >> 5;
    const int wsrc = w >> 1;      // src-tile 0..3
    const int h    = w & 1;       // target half 0..1

    // ---- stage B fragments: 4 consecutive targets/thread ----
    {
        const float* tb = coord_t + (size_t)b * S * 3;
        for (int g = tid; g * 4 < S; g += THREADS) {
            const float4* g4 = reinterpret_cast<const float4*>(tb) + (size_t)g * 3;
            const float4 q0 = g4[0], q1 = g4[1], q2 = g4[2];
            const float px[4] = {q0.x, q0.w, q1.z, q2.y};
            const float py[4] = {q0.y, q1.x, q1.w, q2.z};
            const float pz[4] = {q0.z, q1.y, q2.x, q2.w};
            #pragma unroll
            for (int k = 0; k < 4; ++k) {
                const float tx = px[k], ty = py[k], tz = pz[k];
                const float TN = __builtin_fmaf(tz, tz, __builtin_fmaf(ty, ty, tx*tx));
                const unsigned uhx = f16b(-2.f*tx), uhy = f16b(-2.f*ty), uhz = f16b(-2.f*tz);
                const unsigned TNh = f16b(TN);
                const unsigned TNl = f16b(TN - f16tof((unsigned short)TNh));
                uint4 wv;
                wv.x = uhx | (uhy << 16);
                wv.y = uhz | (uhx << 16);
                wv.z = uhy | (uhz << 16);
                wv.w = TNh | (TNl << 16);
                Bfrag[g * 4 + k] = wv;
            }
        }
    }

    // ---- A fragment: transformed source, fp16 hi/lo split ----
    half8 afrag;
    #pragma unroll
    for (int i = 0; i < 8; ++i) afrag[i] = (_Float16)0.0f;
    {
        const float* Rb = Rm + (size_t)b * 9;
        const float r00=Rb[0], r01=Rb[1], r02=Rb[2];
        const float r10=Rb[3], r11=Rb[4], r12=Rb[5];
        const float r20=Rb[6], r21=Rb[7], r22=Rb[8];
        const float t0=tv[3*b], t1=tv[3*b+1], t2=tv[3*b+2];

        const float* sp = coord + ((size_t)b*S + (size_t)sc*SRC_BLK + wsrc*32 + col) * 3;
        const float x = sp[0], y = sp[1], z = sp[2];
        const float sx = __builtin_fmaf(r00,x,__builtin_fmaf(r01,y,__builtin_fmaf(r02,z,t0)));
        const float sy = __builtin_fmaf(r10,x,__builtin_fmaf(r11,y,__builtin_fmaf(r12,z,t1)));
        const float sz = __builtin_fmaf(r20,x,__builtin_fmaf(r21,y,__builtin_fmaf(r22,z,t2)));
        const float SN = __builtin_fmaf(sz, sz, __builtin_fmaf(sy, sy, sx*sx));
        if (h == 0 && kh == 0) SN_lds[wsrc*32 + col] = SN;
        if (kh == 0) {
            const _Float16 shx = (_Float16)sx, shy = (_Float16)sy, shz = (_Float16)sz;
            afrag[0] = shx; afrag[1] = shy; afrag[2] = shz;
            afrag[3] = (_Float16)(sx - (float)shx);
            afrag[4] = (_Float16)(sy - (float)shy);
            afrag[5] = (_Float16)(sz - (float)shz);
            afrag[6] = (_Float16)1.0f; afrag[7] = (_Float16)1.0f;
        }
    }

    __syncthreads();

    // ---- main loop: 32 target tiles per wave, 2 per iteration ----
    f32x16 zf, mn;
    #pragma unroll
    for (int r = 0; r < 16; ++r) { zf[r] = 0.0f; mn[r] = 1e30f; }

    const uint4* Bp = &Bfrag[h*1024 + col];
    const int nit = S >> 7;                       // 16
    for (int it = 0; it < nit; ++it) {
        const half8 b0 = *reinterpret_cast<const half8*>(Bp + it*64);
        const half8 b1 = *reinterpret_cast<const half8*>(Bp + it*64 + 32);
        const f32x16 aA = __builtin_amdgcn_mfma_f32_32x32x16_f16(afrag, b0, zf, 0, 0, 0);
        const f32x16 aB = __builtin_amdgcn_mfma_f32_32x32x16_f16(afrag, b1, zf, 0, 0, 0);
        #pragma unroll
        for (int r = 0; r < 16; ++r)
            mn[r] = fminf(fminf(mn[r], aA[r]), aB[r]);    // v_min3
    }

    // ---- col prereduce (groups of 4) + write to padded part[] ----
    #pragma unroll
    for (int r = 0; r < 16; ++r) {
        float v = mn[r];
        v = fminf(v, __shfl_xor(v, 1, 64));
        v = fminf(v, __shfl_xor(v, 2, 64));
        if ((col & 3) == 0) {
            const int row = (r & 3) + 8*(r >> 2) + 4*kh;
            part[(wsrc*32 + row)*PART_STRIDE + h*8 + (col >> 2)] = v;
        }
    }
    __syncthreads();

    // ---- combine 16 partials/source, add |s|^2, clamp, block sum ----
    float acc = 0.0f;
    if (tid < 128) {
        const float* pp = &part[tid * PART_STRIDE];
        float m = pp[0];
        #pragma unroll
        for (int j = 1; j < 16; ++j) m = fminf(m, pp[j]);
        acc = fmaxf(SN_lds[tid] + m, 0.0f);
        #pragma unroll
        for (int off = 32; off > 0; off >>= 1) acc += __shfl_down(acc, off, 64);
        if ((tid & 63) == 0) wsum[tid >> 6] = acc;
    }
    __syncthreads();

    // ---- single-dispatch tail: atomic sum + ticket; winner writes out ----
    if (tid == 0) {
        const float bsum = wsum[0] + wsum[1];
        (void)__hip_atomic_fetch_add(sum_p, bsum, __ATOMIC_RELAXED,
                                     __HIP_MEMORY_SCOPE_AGENT);
        // ensure my sum-add is acked before my ticket is visible
        asm volatile("s_waitcnt vmcnt(0)" ::: "memory");
        const unsigned t = __hip_atomic_fetch_add(cnt_p, 1u, __ATOMIC_RELAXED,
                                                  __HIP_MEMORY_SCOPE_AGENT);
        if ((t % (unsigned)nblk) == (unsigned)(nblk - 1)) {
            // all 256 sum-adds complete (each acked before its ticket);
            // read the total through the atomic point itself
            const float total = __hip_atomic_fetch_add(sum_p, 0.0f,
                                 __ATOMIC_RELAXED, __HIP_MEMORY_SCOPE_AGENT);
            out[0] = total * scale;
            __hip_atomic_store(sum_p, 0.0f, __ATOMIC_RELAXED,
                               __HIP_MEMORY_SCOPE_AGENT);   // reset for next replay
        }
    }
}

extern "C" void kernel_launch(void* const* d_in, const int* in_sizes, int n_in,
                              void* d_out, int out_size, void* d_ws, size_t ws_size,
                              hipStream_t stream) {
    const float* coord   = (const float*)d_in[0];
    const float* coord_t = (const float*)d_in[1];
    const float* Rm      = (const float*)d_in[2];
    const float* tv      = (const float*)d_in[3];

    const int B = in_sizes[2] / 9;            // R is [B,3,3]
    const int S = in_sizes[0] / (3 * B);      // coord is [B*S,3]
    const int NSC = S / SRC_BLK;              // 16
    const int nblk = B * NSC;                 // 256

    float* sum_p = (float*)d_ws;
    unsigned int* cnt_p = (unsigned int*)((char*)d_ws + 4);
    float* out = (float*)d_out;

    nn_mfma_kernel<<<nblk, THREADS, 0, stream>>>(
        coord, coord_t, Rm, tv, sum_p, cnt_p, out,
        S, NSC, nblk, 1.0f / ((float)B * (float)S));
}

// Round 14
// 12.215 us; speedup vs baseline: 1.4014x; 1.4014x over previous
//
#include <hip/hip_runtime.h>
#include <math.h>

// NN-MSE (one-directional Chamfer) via MFMA — SINGLE dispatch, contention-free
// tail. k1 compute body identical to R8 (12.2us, absmax 0).
//
// R13 post-mortem: 512 same-cacheline RMWs serialize at one coherence-point
// slice (~17ns each = 8.5us). R14 tail spreads every hot word onto its OWN
// 64B line and minimizes serialized RMWs:
//   1. block -> relaxed ATOMIC STORE of its partial to slot[bid] (own line;
//      256 parallel stores, no RMW)
//   2. s_waitcnt vmcnt(0)  (ack store before ticket)
//   3. ticket on group counter gcnt[bid&31] (32 lines; 8 RMWs each, parallel)
//   4. group-last (t1%8==7) -> ticket on ONE level-2 counter (32 RMWs total)
//   5. level-2-last (t2%32==31) = winner: 256 parallel atomic loads of slots,
//      fixed-order block reduce, out[0] = total*scale.
// Ack chain: winner ticket => all 32 group-lasts => all 256 slot stores acked
// => atomic loads see finals. Mod tests are poison/replay-proof; slots are
// overwritten each call; summation order fixed -> deterministic output.
//
// Math (verified R8): d2(n,m) = |s_n|^2 + (|t_m|^2 - 2 s_n.t_m); cross term
// by v_mfma_f32_32x32x16_f16:
//   A lanes<32: [shx,shy,shz,slx,sly,slz,1,1] (fp16 hi/lo split of src); >=32: 0
//   B col lane: [-2tx,-2ty,-2tz,-2tx,-2ty,-2tz,TNh,TNl] fp16, TN=|t|^2 hi/lo
//   C/D: col=lane&31, row=(reg&3)+8*(reg>>2)+4*(lane>>5)  [m74/m101]

#define THREADS 512
#define SRC_BLK 128
#define PART_STRIDE 18

typedef __attribute__((ext_vector_type(8))) _Float16 half8;
typedef __attribute__((ext_vector_type(16))) float f32x16;

__device__ __forceinline__ unsigned short f16b(float x) {
    _Float16 hv = (_Float16)x;
    return __builtin_bit_cast(unsigned short, hv);
}
__device__ __forceinline__ float f16tof(unsigned short u) {
    return (float)__builtin_bit_cast(_Float16, u);
}

__global__ __launch_bounds__(THREADS)
void nn_mfma_kernel(const float* __restrict__ coord,
                    const float* __restrict__ coord_t,
                    const float* __restrict__ Rm,
                    const float* __restrict__ tv,
                    char* __restrict__ wsbase,
                    float* __restrict__ out,
                    int S, int NSC, int nblk, float scale) {
    __shared__ uint4 Bfrag[2048];                 // 32 KB
    __shared__ float part[128 * PART_STRIDE];     // 9 KB
    __shared__ float SN_lds[128];
    __shared__ float wsum[2];
    __shared__ float sm2[8];
    __shared__ int   winflag;

    const int tid  = threadIdx.x;
    const int bid  = blockIdx.x;
    const int b    = bid / NSC;
    const int sc   = bid - b * NSC;
    const int w    = tid >> 6;
    const int lane = tid & 63;
    const int col  = lane & 31;
    const int kh   = lane >> 5;
    const int wsrc = w >> 1;      // src-tile 0..3
    const int h    = w & 1;       // target half 0..1

    // ---- stage B fragments: 4 consecutive targets/thread ----
    {
        const float* tb = coord_t + (size_t)b * S * 3;
        for (int g = tid; g * 4 < S; g += THREADS) {
            const float4* g4 = reinterpret_cast<const float4*>(tb) + (size_t)g * 3;
            const float4 q0 = g4[0], q1 = g4[1], q2 = g4[2];
            const float px[4] = {q0.x, q0.w, q1.z, q2.y};
            const float py[4] = {q0.y, q1.x, q1.w, q2.z};
            const float pz[4] = {q0.z, q1.y, q2.x, q2.w};
            #pragma unroll
            for (int k = 0; k < 4; ++k) {
                const float tx = px[k], ty = py[k], tz = pz[k];
                const float TN = __builtin_fmaf(tz, tz, __builtin_fmaf(ty, ty, tx*tx));
                const unsigned uhx = f16b(-2.f*tx), uhy = f16b(-2.f*ty), uhz = f16b(-2.f*tz);
                const unsigned TNh = f16b(TN);
                const unsigned TNl = f16b(TN - f16tof((unsigned short)TNh));
                uint4 wv;
                wv.x = uhx | (uhy << 16);
                wv.y = uhz | (uhx << 16);
                wv.z = uhy | (uhz << 16);
                wv.w = TNh | (TNl << 16);
                Bfrag[g * 4 + k] = wv;
            }
        }
    }

    // ---- A fragment: transformed source, fp16 hi/lo split ----
    half8 afrag;
    #pragma unroll
    for (int i = 0; i < 8; ++i) afrag[i] = (_Float16)0.0f;
    {
        const float* Rb = Rm + (size_t)b * 9;
        const float r00=Rb[0], r01=Rb[1], r02=Rb[2];
        const float r10=Rb[3], r11=Rb[4], r12=Rb[5];
        const float r20=Rb[6], r21=Rb[7], r22=Rb[8];
        const float t0=tv[3*b], t1=tv[3*b+1], t2=tv[3*b+2];

        const float* sp = coord + ((size_t)b*S + (size_t)sc*SRC_BLK + wsrc*32 + col) * 3;
        const float x = sp[0], y = sp[1], z = sp[2];
        const float sx = __builtin_fmaf(r00,x,__builtin_fmaf(r01,y,__builtin_fmaf(r02,z,t0)));
        const float sy = __builtin_fmaf(r10,x,__builtin_fmaf(r11,y,__builtin_fmaf(r12,z,t1)));
        const float sz = __builtin_fmaf(r20,x,__builtin_fmaf(r21,y,__builtin_fmaf(r22,z,t2)));
        const float SN = __builtin_fmaf(sz, sz, __builtin_fmaf(sy, sy, sx*sx));
        if (h == 0 && kh == 0) SN_lds[wsrc*32 + col] = SN;
        if (kh == 0) {
            const _Float16 shx = (_Float16)sx, shy = (_Float16)sy, shz = (_Float16)sz;
            afrag[0] = shx; afrag[1] = shy; afrag[2] = shz;
            afrag[3] = (_Float16)(sx - (float)shx);
            afrag[4] = (_Float16)(sy - (float)shy);
            afrag[5] = (_Float16)(sz - (float)shz);
            afrag[6] = (_Float16)1.0f; afrag[7] = (_Float16)1.0f;
        }
    }

    __syncthreads();

    // ---- main loop: 32 target tiles per wave, 2 per iteration ----
    f32x16 zf, mn;
    #pragma unroll
    for (int r = 0; r < 16; ++r) { zf[r] = 0.0f; mn[r] = 1e30f; }

    const uint4* Bp = &Bfrag[h*1024 + col];
    const int nit = S >> 7;                       // 16
    for (int it = 0; it < nit; ++it) {
        const half8 b0 = *reinterpret_cast<const half8*>(Bp + it*64);
        const half8 b1 = *reinterpret_cast<const half8*>(Bp + it*64 + 32);
        const f32x16 aA = __builtin_amdgcn_mfma_f32_32x32x16_f16(afrag, b0, zf, 0, 0, 0);
        const f32x16 aB = __builtin_amdgcn_mfma_f32_32x32x16_f16(afrag, b1, zf, 0, 0, 0);
        #pragma unroll
        for (int r = 0; r < 16; ++r)
            mn[r] = fminf(fminf(mn[r], aA[r]), aB[r]);    // v_min3
    }

    // ---- col prereduce (groups of 4) + write to padded part[] ----
    #pragma unroll
    for (int r = 0; r < 16; ++r) {
        float v = mn[r];
        v = fminf(v, __shfl_xor(v, 1, 64));
        v = fminf(v, __shfl_xor(v, 2, 64));
        if ((col & 3) == 0) {
            const int row = (r & 3) + 8*(r >> 2) + 4*kh;
            part[(wsrc*32 + row)*PART_STRIDE + h*8 + (col >> 2)] = v;
        }
    }
    __syncthreads();

    // ---- combine 16 partials/source, add |s|^2, clamp, block sum ----
    float acc = 0.0f;
    if (tid < 128) {
        const float* pp = &part[tid * PART_STRIDE];
        float m = pp[0];
        #pragma unroll
        for (int j = 1; j < 16; ++j) m = fminf(m, pp[j]);
        acc = fmaxf(SN_lds[tid] + m, 0.0f);
        #pragma unroll
        for (int off = 32; off > 0; off >>= 1) acc += __shfl_down(acc, off, 64);
        if ((tid & 63) == 0) wsum[tid >> 6] = acc;
    }
    __syncthreads();

    // ---- contention-free single-dispatch tail ----
    // layout in ws: slot[bid] at bid*64; gcnt[g] at 16384+g*64; c2 at 16384+2048
    if (tid == 0) {
        winflag = 0;
        const float bsum = wsum[0] + wsum[1];
        float* slot = (float*)(wsbase + (size_t)bid * 64);
        __hip_atomic_store(slot, bsum, __ATOMIC_RELAXED, __HIP_MEMORY_SCOPE_AGENT);
        asm volatile("s_waitcnt vmcnt(0)" ::: "memory");   // ack slot store
        unsigned* gcnt = (unsigned*)(wsbase + 16384 + (size_t)(bid & 31) * 64);
        const unsigned t1 = __hip_atomic_fetch_add(gcnt, 1u, __ATOMIC_RELAXED,
                                                   __HIP_MEMORY_SCOPE_AGENT);
        if ((t1 & 7u) == 7u) {                  // last of my 8-block group
            unsigned* c2 = (unsigned*)(wsbase + 16384 + 2048);
            const unsigned t2 = __hip_atomic_fetch_add(c2, 1u, __ATOMIC_RELAXED,
                                                       __HIP_MEMORY_SCOPE_AGENT);
            if ((t2 & 31u) == 31u) winflag = 1; // last of 32 groups = winner
        }
    }
    __syncthreads();

    if (winflag) {
        float v = 0.0f;
        if (tid < nblk) {
            const float* slot = (const float*)(wsbase + (size_t)tid * 64);
            v = __hip_atomic_load(slot, __ATOMIC_RELAXED, __HIP_MEMORY_SCOPE_AGENT);
        }
        #pragma unroll
        for (int off = 32; off > 0; off >>= 1) v += __shfl_down(v, off, 64);
        if ((tid & 63) == 0) sm2[tid >> 6] = v;
        __syncthreads();
        if (tid == 0) {
            float tot = 0.0f;
            #pragma unroll
            for (int i = 0; i < 8; ++i) tot += sm2[i];
            out[0] = tot * scale;
        }
    }
}

extern "C" void kernel_launch(void* const* d_in, const int* in_sizes, int n_in,
                              void* d_out, int out_size, void* d_ws, size_t ws_size,
                              hipStream_t stream) {
    const float* coord   = (const float*)d_in[0];
    const float* coord_t = (const float*)d_in[1];
    const float* Rm      = (const float*)d_in[2];
    const float* tv      = (const float*)d_in[3];

    const int B = in_sizes[2] / 9;            // R is [B,3,3]
    const int S = in_sizes[0] / (3 * B);      // coord is [B*S,3]
    const int NSC = S / SRC_BLK;              // 16
    const int nblk = B * NSC;                 // 256

    nn_mfma_kernel<<<nblk, THREADS, 0, stream>>>(
        coord, coord_t, Rm, tv, (char*)d_ws, (float*)d_out,
        S, NSC, nblk, 1.0f / ((float)B * (float)S));
}